// Round 4
// baseline (2406.090 us; speedup 1.0000x reference)
//
#include <hip/hip_runtime.h>
#include <math.h>

#define SEQ 2048
#define BATCH 64
#define INF 256
#define HID 256
#define NL 2

// ---------------------------------------------------------------------------
// Phase A: pre[l][m][h] = sum_i x[m][i] * W[l][h][i] + bias[l][h]
// (unchanged — ~550 us; optimize after rnn_kernel hits its floor)
// ---------------------------------------------------------------------------
__global__ __launch_bounds__(256) void xw_kernel(
    const float* __restrict__ x,
    const float* __restrict__ W,
    const float* __restrict__ bias,
    float* __restrict__ pre0,
    float* __restrict__ pre1)
{
    __shared__ float As[64][68];
    __shared__ float Bs[64][68];

    const int mb = blockIdx.x * 64;
    const int nb = blockIdx.y * 64;
    const int l  = nb >> 8;
    const int hb = nb & 255;

    const int tid = threadIdx.x;
    const int tx = tid & 15;
    const int ty = tid >> 4;

    const float* Wl = W + (size_t)l * HID * INF;

    float acc[4][4] = {};

    const int lrow = tid >> 4;
    const int lkq  = tid & 15;

    for (int kb = 0; kb < INF; kb += 64) {
        #pragma unroll
        for (int rr = 0; rr < 4; ++rr) {
            const int m = lrow + rr * 16;
            float4 va = *(const float4*)&x[(size_t)(mb + m) * INF + kb + lkq * 4];
            As[lkq*4 + 0][m] = va.x; As[lkq*4 + 1][m] = va.y;
            As[lkq*4 + 2][m] = va.z; As[lkq*4 + 3][m] = va.w;
            float4 vb = *(const float4*)&Wl[(size_t)(hb + m) * INF + kb + lkq * 4];
            Bs[lkq*4 + 0][m] = vb.x; Bs[lkq*4 + 1][m] = vb.y;
            Bs[lkq*4 + 2][m] = vb.z; Bs[lkq*4 + 3][m] = vb.w;
        }
        __syncthreads();

        #pragma unroll 8
        for (int k = 0; k < 64; ++k) {
            float4 a = *(const float4*)&As[k][ty * 4];
            float4 b = *(const float4*)&Bs[k][tx * 4];
            acc[0][0] = fmaf(a.x, b.x, acc[0][0]);
            acc[0][1] = fmaf(a.x, b.y, acc[0][1]);
            acc[0][2] = fmaf(a.x, b.z, acc[0][2]);
            acc[0][3] = fmaf(a.x, b.w, acc[0][3]);
            acc[1][0] = fmaf(a.y, b.x, acc[1][0]);
            acc[1][1] = fmaf(a.y, b.y, acc[1][1]);
            acc[1][2] = fmaf(a.y, b.z, acc[1][2]);
            acc[1][3] = fmaf(a.y, b.w, acc[1][3]);
            acc[2][0] = fmaf(a.z, b.x, acc[2][0]);
            acc[2][1] = fmaf(a.z, b.y, acc[2][1]);
            acc[2][2] = fmaf(a.z, b.z, acc[2][2]);
            acc[2][3] = fmaf(a.z, b.w, acc[2][3]);
            acc[3][0] = fmaf(a.w, b.x, acc[3][0]);
            acc[3][1] = fmaf(a.w, b.y, acc[3][1]);
            acc[3][2] = fmaf(a.w, b.z, acc[3][2]);
            acc[3][3] = fmaf(a.w, b.w, acc[3][3]);
        }
        __syncthreads();
    }

    float bv[4];
    #pragma unroll
    for (int j = 0; j < 4; ++j)
        bv[j] = bias[l * HID + hb + tx * 4 + j];

    float* dst = (l == 0) ? pre0 : pre1;
    #pragma unroll
    for (int i = 0; i < 4; ++i) {
        float4 o;
        o.x = acc[i][0] + bv[0];
        o.y = acc[i][1] + bv[1];
        o.z = acc[i][2] + bv[2];
        o.w = acc[i][3] + bv[3];
        *(float4*)&dst[(size_t)(mb + ty * 4 + i) * HID + hb + tx * 4] = o;
    }
}

// fast tanh: clamp + hw exp. |err| ~1e-6 rel, fine vs 2e-2 threshold.
__device__ __forceinline__ float tanh_fast(float x) {
    float xc = fminf(fmaxf(x, -12.0f), 12.0f);
    float e  = __expf(2.0f * xc);            // v_exp_f32 path
    return __fdividef(e - 1.0f, e + 1.0f);   // v_rcp + mul
}

// ---------------------------------------------------------------------------
// Phase B v3: identical structure to v2, but U registers are PINNED with an
// opaque empty-asm redefinition so the backend cannot rematerialize the
// global loads inside the step loop (round-1/3 evidence: VGPR_Count=48 means
// u4[] was re-loaded from L1 every step -> latency-bound, 3.8x issue floor).
// ---------------------------------------------------------------------------
__global__ __launch_bounds__(1024, 4) void rnn_kernel(
    const float* __restrict__ h0,
    const float* __restrict__ U,
    const float* pre0,
    const float* pre1,
    float* out,
    float* hn)
{
    __shared__ float h_lds[2][4][72];

    const int l = blockIdx.x >> 6;
    const int b = blockIdx.x & 63;
    const int tid = threadIdx.x;
    const int g = tid >> 2;           // 0..255
    const int c = tid & 3;            // 0..3

    // pin U[l][g][c*64 .. c*64+63] in registers
    float4 u4[16];
    const float* Urow = U + (size_t)l * HID * HID + (size_t)g * HID + c * 64;
    #pragma unroll
    for (int q = 0; q < 16; ++q)
        u4[q] = *(const float4*)&Urow[q * 4];

    // Opaque redefinition: forces all 64 U values to live in VGPRs for the
    // whole kernel; the compiler can no longer fold/remat the loads into the
    // loop body.
    #pragma unroll
    for (int q = 0; q < 16; ++q)
        asm volatile("" : "+v"(u4[q].x), "+v"(u4[q].y), "+v"(u4[q].z), "+v"(u4[q].w));

    if (tid < HID)
        h_lds[0][tid >> 6][tid & 63] = h0[(size_t)l * BATCH * HID + (size_t)b * HID + tid];
    __syncthreads();

    const float* pre = (l == 0) ? pre0 : pre1;
    const size_t bh = (size_t)b * HID + g;

    float preCur = pre[bh];           // t = 0 (redundant across 4 lanes, cached)
    float v = 0.0f;
    int cur = 0;

    for (int t = 0; t < SEQ; ++t) {
        // prefetch next pre early so HBM latency hides under the FMAs
        float preNext = (t + 1 < SEQ) ? pre[(size_t)(t + 1) * BATCH * HID + bh] : 0.0f;

        float a0 = 0.f, a1 = 0.f, a2 = 0.f, a3 = 0.f;
        const float* hseg = &h_lds[cur][c][0];
        #pragma unroll
        for (int q = 0; q < 16; ++q) {
            float4 hv = *(const float4*)&hseg[q * 4];
            a0 = fmaf(u4[q].x, hv.x, a0);
            a1 = fmaf(u4[q].y, hv.y, a1);
            a2 = fmaf(u4[q].z, hv.z, a2);
            a3 = fmaf(u4[q].w, hv.w, a3);
        }
        float s = (a0 + a1) + (a2 + a3);
        s += __shfl_xor(s, 1);
        s += __shfl_xor(s, 2);        // all 4 lanes now hold the full dot

        v = tanh_fast(s + preCur);

        if (c == 0) {
            h_lds[cur ^ 1][g >> 6][g & 63] = v;
            if (l == 1)
                out[(size_t)t * BATCH * HID + bh] = v;
        }
        preCur = preNext;
        cur ^= 1;
        __syncthreads();
    }

    if (c == 0)
        hn[(size_t)l * BATCH * HID + bh] = v;
}

extern "C" void kernel_launch(void* const* d_in, const int* in_sizes, int n_in,
                              void* d_out, int out_size, void* d_ws, size_t ws_size,
                              hipStream_t stream) {
    const float* x  = (const float*)d_in[0];   // [SEQ][B][IN]
    const float* h0 = (const float*)d_in[1];   // [L][B][H]
    const float* W  = (const float*)d_in[2];   // [L][H][IN]
    const float* U  = (const float*)d_in[3];   // [L][H][H]
    const float* bs = (const float*)d_in[4];   // [L][H]

    float* out  = (float*)d_out;               // [SEQ][B][H] then [L][B][H]
    float* pre0 = (float*)d_ws;                // l=0 preacts (134 MB)
    float* pre1 = out;                         // l=1 preacts staged in-place
    float* hn   = out + (size_t)SEQ * BATCH * HID;

    dim3 gridA(SEQ * BATCH / 64, (NL * HID) / 64);
    xw_kernel<<<gridA, 256, 0, stream>>>(x, W, bs, pre0, pre1);

    rnn_kernel<<<NL * BATCH, 1024, 0, stream>>>(h0, U, pre0, pre1, out, hn);
}